// Round 2
// baseline (513.451 us; speedup 1.0000x reference)
//
#include <hip/hip_runtime.h>
#include <hip/hip_bf16.h>
#include <stdint.h>

// Sizes (fixed by the problem)
#define NN 512
#define DD 128
#define EE 16384
#define K3 384

typedef short bf16x8 __attribute__((ext_vector_type(8)));
typedef short bf16x4 __attribute__((ext_vector_type(4)));
typedef float f32x4  __attribute__((ext_vector_type(4)));

__device__ __forceinline__ short f2bf(float f) {
    union { __hip_bfloat16 h; short s; } u;
    u.h = __float2bfloat16(f);
    return u.s;
}

// async global->LDS 16B copy. HW semantics: LDS dest = wave-uniform base +
// lane*16; we always pass per-lane pointers that follow exactly that layout.
typedef __attribute__((address_space(3))) unsigned int lds_u32;
typedef __attribute__((address_space(1))) const unsigned int glb_u32;
__device__ __forceinline__ void gll16(void* l, const void* g) {
    __builtin_amdgcn_global_load_lds((glb_u32*)g, (lds_u32*)l, 16, 0, 0);
}

// ---------------- tiny prep kernels ----------------

__global__ void k_zero(float* __restrict__ At) {
    At[blockIdx.x * 256 + threadIdx.x] = 0.0f;
}

// Build At[dst][src] += 1.  Robust to int32 (harness doc) or int64 (reference)
// edge_index: for int64 LE, every odd 32-bit word is 0 (values < 512).
__global__ void k_edges(const int* __restrict__ ei, float* __restrict__ At) {
    __shared__ int flag;
    if (threadIdx.x == 0) flag = 0;
    __syncthreads();
    int any = 0;
    for (int i = threadIdx.x; i < EE; i += blockDim.x) any |= ei[2 * i + 1];
    if (any) atomicOr(&flag, 1);
    __syncthreads();
    const bool is32 = (flag != 0);
    for (int e = threadIdx.x; e < EE; e += blockDim.x) {
        int src, dst;
        if (is32) { src = ei[e];     dst = ei[EE + e]; }
        else      { src = ei[2 * e]; dst = ei[2 * (EE + e)]; }
        atomicAdd(&At[dst * NN + src], 1.0f);
    }
}

__global__ void k_cast_at(const float* __restrict__ At, short* __restrict__ Atb) {
    int t = blockIdx.x * 256 + threadIdx.x;
    Atb[t] = f2bf(At[t]);
}

// Wt[n][kk] = bf16(W[kk][n])
__global__ void k_wt(const float* __restrict__ W, short* __restrict__ Wt) {
    int t = blockIdx.x * 256 + threadIdx.x;     // t = kk*128 + n
    int kk = t >> 7, n = t & 127;
    Wt[n * K3 + kk] = f2bf(W[t]);
}

// ---------------- transpose prep ----------------
// blocks 0..2047:  XbT[i][d][k] = bf16(X[i][k][d])    (i = b>>2, k0 = (b&3)*128)
// blocks 2048.. :  XT2[j][d][i] = bf16(X[i][j][d])    (j, i0 likewise)
// LDS tile [128 rows][128 cols] column-swizzled by ((row>>3)&7)<<2 so the
// transpose-gather reads spread over 8 banks (2-way, free).
__global__ __launch_bounds__(256) void k_prep(const float* __restrict__ X,
                                              short* __restrict__ XbT,
                                              short* __restrict__ XT2) {
    __shared__ __align__(16) short T[128 * 128];
    const int tid = threadIdx.x;
    const int b = blockIdx.x;
    int sbase, rstride, dbase;
    short* dst;
    if (b < 2048) {
        int i = b >> 2, k0 = (b & 3) * 128;
        sbase = i * 65536 + k0 * 128; rstride = 128;    // row r -> X[i][k0+r][*]
        dbase = i * 65536 + k0; dst = XbT;
    } else {
        int bb = b - 2048;
        int j = bb >> 2, i0 = (bb & 3) * 128;
        sbase = i0 * 65536 + j * 128; rstride = 65536;  // row r -> X[i0+r][j][*]
        dbase = j * 65536 + i0; dst = XT2;
    }
    #pragma unroll
    for (int it = 0; it < 16; ++it) {
        int g = tid + it * 256;
        int r = g >> 5, c4 = (g & 31) * 4;
        float4 v = *(const float4*)&X[sbase + r * rstride + c4];
        bf16x4 p; p[0] = f2bf(v.x); p[1] = f2bf(v.y); p[2] = f2bf(v.z); p[3] = f2bf(v.w);
        int cs = c4 ^ (((r >> 3) & 7) << 2);
        *(bf16x4*)&T[r * 128 + cs] = p;
    }
    __syncthreads();
    #pragma unroll
    for (int it = 0; it < 8; ++it) {
        int q = tid + it * 256;
        int d = q >> 4, ck = (q & 15) * 8;
        bf16x8 p;
        #pragma unroll
        for (int j = 0; j < 8; ++j) {
            int k = ck + j;
            p[j] = T[k * 128 + (d ^ (((k >> 3) & 7) << 2))];
        }
        *(bf16x8*)&dst[dbase + d * 512 + ck] = p;
    }
}

// ---------------- aggregation GEMM (m97 structure) ----------------
// C[r,d] = sum_k Atb[a0+r,k] * B[inst][d][k],  128x128 tile, K=512, BK=64.
// mode 0 (X1): inst=i, a0=jt*128, C row-major 128-stride
// mode 1 (X2): inst=j, a0=it*128, C strided 65536
// LDS chunk placement XOR-swizzled: slot (row r, pos p) holds k-chunk p^(r&7).
__global__ __launch_bounds__(256) void k_aggg(const short* __restrict__ Atb,
                                              const short* __restrict__ Bsrc,
                                              short* __restrict__ C,
                                              int mode) {
    __shared__ __align__(16) short sm[16384];
    short* As = sm;
    short* Bs = sm + 8192;

    const int tid  = threadIdx.x;
    const int lane = tid & 63;
    const int wv   = tid >> 6;
    const int wr   = (wv >> 1) * 64;
    const int wc   = (wv & 1) * 64;
    const int lm   = lane & 15;
    const int lq   = lane >> 4;

    const int inst = blockIdx.x >> 2, t4 = blockIdx.x & 3;
    const int a0 = t4 * 128;
    const int Bbase = inst * 65536;
    int Cbase, Crs;
    if (mode == 0) { Cbase = inst * 65536 + t4 * 16384; Crs = 128; }
    else           { Cbase = t4 * 8388608 + inst * 128; Crs = 65536; }

    // per-thread staging coords (fixed across K loop)
    int srow[4], scg[4];
    #pragma unroll
    for (int it = 0; it < 4; ++it) {
        int s = it * 256 + tid;
        int r = s >> 3, p = s & 7;
        srow[it] = r; scg[it] = (p ^ (r & 7)) * 8;
    }

    f32x4 acc[4][4] = {};

    for (int kb = 0; kb < 8; ++kb) {
        const int k0 = kb * 64;
        #pragma unroll
        for (int it = 0; it < 4; ++it) {
            int slot = it * 256 + tid;
            gll16(&As[slot * 8], &Atb[(a0 + srow[it]) * 512 + k0 + scg[it]]);
            gll16(&Bs[slot * 8], &Bsrc[Bbase + srow[it] * 512 + k0 + scg[it]]);
        }
        __syncthreads();      // drains vmcnt -> LDS valid
        #pragma unroll
        for (int ks = 0; ks < 2; ++ks) {
            bf16x8 af[4], bf[4];
            #pragma unroll
            for (int mf = 0; mf < 4; ++mf) {
                int R = wr + mf * 16 + lm, Cc = ks * 4 + lq;
                af[mf] = *(const bf16x8*)&As[R * 64 + (Cc ^ (R & 7)) * 8];
            }
            #pragma unroll
            for (int nf = 0; nf < 4; ++nf) {
                int R = wc + nf * 16 + lm, Cc = ks * 4 + lq;
                bf[nf] = *(const bf16x8*)&Bs[R * 64 + (Cc ^ (R & 7)) * 8];
            }
            #pragma unroll
            for (int mf = 0; mf < 4; ++mf)
                #pragma unroll
                for (int nf = 0; nf < 4; ++nf)
                    acc[mf][nf] = __builtin_amdgcn_mfma_f32_16x16x32_bf16(
                        af[mf], bf[nf], acc[mf][nf], 0, 0, 0);
        }
        __syncthreads();
    }

    // epilogue: LDS round-trip -> coalesced 16B stores
    #pragma unroll
    for (int mf = 0; mf < 4; ++mf)
        #pragma unroll
        for (int nf = 0; nf < 4; ++nf)
            #pragma unroll
            for (int r = 0; r < 4; ++r)
                sm[(wr + mf * 16 + lq * 4 + r) * 128 + wc + nf * 16 + lm]
                    = f2bf(acc[mf][nf][r]);
    __syncthreads();
    #pragma unroll
    for (int it = 0; it < 8; ++it) {
        int q = tid + it * 256;
        int orow = q >> 4, oc = (q & 15) * 8;
        *(bf16x8*)&C[Cbase + orow * Crs + oc] = *(const bf16x8*)&sm[orow * 128 + oc];
    }
}

// ---------------- final fused concat-GEMM ----------------
__global__ __launch_bounds__(256) void k_final2(const float* __restrict__ X,
                                                const short* __restrict__ X1b,
                                                const short* __restrict__ X2b,
                                                const short* __restrict__ Wt,
                                                const float* __restrict__ bias,
                                                float* __restrict__ out) {
    __shared__ __align__(16) short sm[16384];
    short* As = sm;
    short* Ws = sm + 8192;

    const int tid  = threadIdx.x;
    const int lane = tid & 63;
    const int wv   = tid >> 6;
    const int wr   = (wv >> 1) * 64;
    const int wc   = (wv & 1) * 64;
    const int lm   = lane & 15;
    const int lq   = lane >> 4;
    const int m0   = blockIdx.x * 128;

    int srow[4], scg[4];
    #pragma unroll
    for (int it = 0; it < 4; ++it) {
        int s = it * 256 + tid;
        int r = s >> 3, p = s & 7;
        srow[it] = r; scg[it] = (p ^ (r & 7)) * 8;
    }

    f32x4 acc[4][4] = {};

    for (int ph = 0; ph < 6; ++ph) {
        const int s = ph >> 1, h = ph & 1;
        const int kw0 = s * 128 + h * 64;
        if (s == 0) {
            // fp32 X, register-convert, swizzle-consistent placement
            #pragma unroll
            for (int it = 0; it < 4; ++it) {
                int slot = it * 256 + tid;
                const float* xp = &X[(m0 + srow[it]) * 128 + h * 64 + scg[it]];
                float4 v0 = *(const float4*)xp;
                float4 v1 = *(const float4*)(xp + 4);
                bf16x8 pk;
                pk[0] = f2bf(v0.x); pk[1] = f2bf(v0.y); pk[2] = f2bf(v0.z); pk[3] = f2bf(v0.w);
                pk[4] = f2bf(v1.x); pk[5] = f2bf(v1.y); pk[6] = f2bf(v1.z); pk[7] = f2bf(v1.w);
                *(bf16x8*)&As[slot * 8] = pk;
            }
        } else {
            const short* src = (s == 1) ? X1b : X2b;
            #pragma unroll
            for (int it = 0; it < 4; ++it)
                gll16(&As[(it * 256 + tid) * 8],
                      &src[(m0 + srow[it]) * 128 + h * 64 + scg[it]]);
        }
        #pragma unroll
        for (int it = 0; it < 4; ++it)
            gll16(&Ws[(it * 256 + tid) * 8],
                  &Wt[srow[it] * K3 + kw0 + scg[it]]);
        __syncthreads();
        #pragma unroll
        for (int ks = 0; ks < 2; ++ks) {
            bf16x8 af[4], bf[4];
            #pragma unroll
            for (int mf = 0; mf < 4; ++mf) {
                int R = wr + mf * 16 + lm, Cc = ks * 4 + lq;
                af[mf] = *(const bf16x8*)&As[R * 64 + (Cc ^ (R & 7)) * 8];
            }
            #pragma unroll
            for (int nf = 0; nf < 4; ++nf) {
                int R = wc + nf * 16 + lm, Cc = ks * 4 + lq;
                bf[nf] = *(const bf16x8*)&Ws[R * 64 + (Cc ^ (R & 7)) * 8];
            }
            #pragma unroll
            for (int mf = 0; mf < 4; ++mf)
                #pragma unroll
                for (int nf = 0; nf < 4; ++nf)
                    acc[mf][nf] = __builtin_amdgcn_mfma_f32_16x16x32_bf16(
                        af[mf], bf[nf], acc[mf][nf], 0, 0, 0);
        }
        __syncthreads();
    }

    #pragma unroll
    for (int nf = 0; nf < 4; ++nf) {
        float bv = bias[wc + nf * 16 + lm];
        #pragma unroll
        for (int mf = 0; mf < 4; ++mf)
            #pragma unroll
            for (int r = 0; r < 4; ++r) {
                int row = m0 + wr + mf * 16 + lq * 4 + r;
                int col = wc + nf * 16 + lm;
                out[row * 128 + col] = acc[mf][nf][r] + bv;
            }
    }
}

// ================= fallback path (round-1, proven, 130 MiB ws) =================

__global__ __launch_bounds__(256) void k_agg_fb(const float* __restrict__ X,
                                                const float* __restrict__ At,
                                                short* __restrict__ X1b,
                                                short* __restrict__ X2b) {
    __shared__ short As[128 * 72];
    __shared__ short Bs[128 * 72];
    const int tid  = threadIdx.x;
    const int lane = tid & 63;
    const int wv   = tid >> 6;
    const int wr   = (wv >> 1) * 64;
    const int wc   = (wv & 1) * 64;
    const int lm   = lane & 15;
    const int lq   = lane >> 4;
    int a0, Bbase, Bks, Cbase, Crs;
    short* Cp;
    const int bidx = blockIdx.x;
    if (bidx < 2048) {
        int i = bidx >> 2, jt = bidx & 3;
        a0 = jt * 128; Bbase = i * 65536; Bks = 128;
        Cbase = i * 65536 + jt * 16384; Crs = 128; Cp = X1b;
    } else {
        int bb = bidx - 2048;
        int j = bb >> 2, it = bb & 3;
        a0 = it * 128; Bbase = j * 128; Bks = 65536;
        Cbase = it * 8388608 + j * 128; Crs = 65536; Cp = X2b;
    }
    f32x4 acc[4][4] = {};
    const int d  = tid & 127;
    const int kh = tid >> 7;
    for (int kb = 0; kb < 8; ++kb) {
        const int k0 = kb * 64;
        #pragma unroll
        for (int it8 = 0; it8 < 8; ++it8) {
            int g = tid + it8 * 256;
            int r = g >> 4, kq = (g & 15) * 4;
            float4 v = *(const float4*)&At[(a0 + r) * 512 + k0 + kq];
            bf16x4 p; p[0] = f2bf(v.x); p[1] = f2bf(v.y); p[2] = f2bf(v.z); p[3] = f2bf(v.w);
            *(bf16x4*)&As[r * 72 + kq] = p;
        }
        #pragma unroll
        for (int gi = 0; gi < 4; ++gi) {
            int kg = kh * 4 + gi;
            bf16x8 p;
            #pragma unroll
            for (int j = 0; j < 8; ++j)
                p[j] = f2bf(X[Bbase + (k0 + kg * 8 + j) * Bks + d]);
            *(bf16x8*)&Bs[d * 72 + kg * 8] = p;
        }
        __syncthreads();
        #pragma unroll
        for (int ks = 0; ks < 2; ++ks) {
            bf16x8 af[4], bfr[4];
            #pragma unroll
            for (int mf = 0; mf < 4; ++mf)
                af[mf] = *(const bf16x8*)&As[(wr + mf * 16 + lm) * 72 + ks * 32 + lq * 8];
            #pragma unroll
            for (int nf = 0; nf < 4; ++nf)
                bfr[nf] = *(const bf16x8*)&Bs[(wc + nf * 16 + lm) * 72 + ks * 32 + lq * 8];
            #pragma unroll
            for (int mf = 0; mf < 4; ++mf)
                #pragma unroll
                for (int nf = 0; nf < 4; ++nf)
                    acc[mf][nf] = __builtin_amdgcn_mfma_f32_16x16x32_bf16(
                        af[mf], bfr[nf], acc[mf][nf], 0, 0, 0);
        }
        __syncthreads();
    }
    #pragma unroll
    for (int mf = 0; mf < 4; ++mf)
        #pragma unroll
        for (int nf = 0; nf < 4; ++nf)
            #pragma unroll
            for (int r = 0; r < 4; ++r) {
                int row = wr + mf * 16 + lq * 4 + r;
                int col = wc + nf * 16 + lm;
                Cp[Cbase + row * Crs + col] = f2bf(acc[mf][nf][r]);
            }
}

__global__ __launch_bounds__(256) void k_final_fb(const float* __restrict__ X,
                                                  const short* __restrict__ X1b,
                                                  const short* __restrict__ X2b,
                                                  const short* __restrict__ Wt,
                                                  const float* __restrict__ bias,
                                                  float* __restrict__ out) {
    __shared__ short As[128 * 72];
    __shared__ short Ws[128 * 72];
    const int tid  = threadIdx.x;
    const int lane = tid & 63;
    const int wv   = tid >> 6;
    const int wr   = (wv >> 1) * 64;
    const int wc   = (wv & 1) * 64;
    const int lm   = lane & 15;
    const int lq   = lane >> 4;
    const int m0   = blockIdx.x * 128;
    f32x4 acc[4][4] = {};
    for (int ph = 0; ph < 6; ++ph) {
        const int s = ph >> 1, h = ph & 1;
        if (s == 0) {
            #pragma unroll
            for (int it8 = 0; it8 < 8; ++it8) {
                int g = tid + it8 * 256;
                int r = g >> 4, kq = (g & 15) * 4;
                float4 v = *(const float4*)&X[(m0 + r) * 128 + h * 64 + kq];
                bf16x4 p; p[0] = f2bf(v.x); p[1] = f2bf(v.y); p[2] = f2bf(v.z); p[3] = f2bf(v.w);
                *(bf16x4*)&As[r * 72 + kq] = p;
            }
        } else {
            const short* src = (s == 1) ? X1b : X2b;
            #pragma unroll
            for (int it4 = 0; it4 < 4; ++it4) {
                int g = tid + it4 * 256;
                int r = g >> 3, ko = (g & 7) * 8;
                *(bf16x8*)&As[r * 72 + ko] =
                    *(const bf16x8*)&src[(m0 + r) * 128 + h * 64 + ko];
            }
        }
        #pragma unroll
        for (int it4 = 0; it4 < 4; ++it4) {
            int g = tid + it4 * 256;
            int n = g >> 3, ko = (g & 7) * 8;
            *(bf16x8*)&Ws[n * 72 + ko] =
                *(const bf16x8*)&Wt[n * K3 + s * 128 + h * 64 + ko];
        }
        __syncthreads();
        #pragma unroll
        for (int ks = 0; ks < 2; ++ks) {
            bf16x8 af[4], bfr[4];
            #pragma unroll
            for (int mf = 0; mf < 4; ++mf)
                af[mf] = *(const bf16x8*)&As[(wr + mf * 16 + lm) * 72 + ks * 32 + lq * 8];
            #pragma unroll
            for (int nf = 0; nf < 4; ++nf)
                bfr[nf] = *(const bf16x8*)&Ws[(wc + nf * 16 + lm) * 72 + ks * 32 + lq * 8];
            #pragma unroll
            for (int mf = 0; mf < 4; ++mf)
                #pragma unroll
                for (int nf = 0; nf < 4; ++nf)
                    acc[mf][nf] = __builtin_amdgcn_mfma_f32_16x16x32_bf16(
                        af[mf], bfr[nf], acc[mf][nf], 0, 0, 0);
        }
        __syncthreads();
    }
    #pragma unroll
    for (int nf = 0; nf < 4; ++nf) {
        float bv = bias[wc + nf * 16 + lm];
        #pragma unroll
        for (int mf = 0; mf < 4; ++mf)
            #pragma unroll
            for (int r = 0; r < 4; ++r) {
                int row = m0 + wr + mf * 16 + lq * 4 + r;
                int col = wc + nf * 16 + lm;
                out[row * 128 + col] = acc[mf][nf][r] + bv;
            }
    }
}

extern "C" void kernel_launch(void* const* d_in, const int* in_sizes, int n_in,
                              void* d_out, int out_size, void* d_ws, size_t ws_size,
                              hipStream_t stream) {
    const float* X  = (const float*)d_in[0];
    const int*   ei = (const int*)d_in[1];
    const float* W  = (const float*)d_in[2];
    const float* b  = (const float*)d_in[3];
    float* out = (float*)d_out;
    char* ws = (char*)d_ws;
    const size_t MB = 1u << 20;

    float* At  = (float*)ws;                 // 1 MiB
    short* Atb = (short*)(ws + 1 * MB);      // 0.5 MiB
    short* Wt  = (short*)(ws + 1 * MB + 512 * 1024);  // 96 KiB

    k_zero <<<1024, 256, 0, stream>>>(At);
    k_edges<<<1, 1024, 0, stream>>>(ei, At);
    k_wt   <<<192, 256, 0, stream>>>(W, Wt);

    if (ws_size >= 194 * MB) {
        // fast path: X1b @2MiB, XT2 @66MiB, XbT @130MiB (reused as X2b after agg1)
        short* X1b = (short*)(ws + 2 * MB);
        short* XT2 = (short*)(ws + 66 * MB);
        short* XbT = (short*)(ws + 130 * MB);
        short* X2b = XbT;   // alias: XbT dead after k_aggg(mode 0)
        k_cast_at<<<1024, 256, 0, stream>>>(At, Atb);
        k_prep   <<<4096, 256, 0, stream>>>(X, XbT, XT2);
        k_aggg   <<<2048, 256, 0, stream>>>(Atb, XbT, X1b, 0);
        k_aggg   <<<2048, 256, 0, stream>>>(Atb, XT2, X2b, 1);
        k_final2 <<<2048, 256, 0, stream>>>(X, X1b, X2b, Wt, b, out);
    } else {
        // fallback: proven round-1 path within 130 MiB
        short* X1b = (short*)(ws + 2 * MB);
        short* X2b = (short*)(ws + 66 * MB);
        k_agg_fb  <<<4096, 256, 0, stream>>>(X, At, X1b, X2b);
        k_final_fb<<<2048, 256, 0, stream>>>(X, X1b, X2b, Wt, b, out);
    }
}

// Round 3
// 475.699 us; speedup vs baseline: 1.0794x; 1.0794x over previous
//
#include <hip/hip_runtime.h>
#include <hip/hip_bf16.h>
#include <stdint.h>

// Sizes (fixed by the problem)
#define NN 512
#define DD 128
#define EE 16384
#define K3 384

typedef short bf16x8 __attribute__((ext_vector_type(8)));
typedef short bf16x4 __attribute__((ext_vector_type(4)));
typedef float f32x4  __attribute__((ext_vector_type(4)));
typedef unsigned int u32;

__device__ __forceinline__ short f2bf(float f) {
    union { __hip_bfloat16 h; short s; } u;
    u.h = __float2bfloat16(f);
    return u.s;
}
__device__ __forceinline__ u32 pk2(float a, float b) {
    return (u32)(unsigned short)f2bf(a) | ((u32)(unsigned short)f2bf(b) << 16);
}

// async global->LDS 16B copy. LDS dest = wave-uniform base + lane*16: dest is
// always linear in tid; the XOR swizzle is applied on the SOURCE chunk index.
typedef __attribute__((address_space(3))) unsigned int lds_u32;
typedef __attribute__((address_space(1))) const unsigned int glb_u32;
__device__ __forceinline__ void gll16(void* l, const void* g) {
    __builtin_amdgcn_global_load_lds((glb_u32*)g, (lds_u32*)l, 16, 0, 0);
}

// ---------------- tiny prep kernels ----------------

__global__ void k_zero(float* __restrict__ At) {
    At[blockIdx.x * 256 + threadIdx.x] = 0.0f;
}

// Build At[dst][src] += 1.  Robust to int32 (harness doc) or int64 (reference):
// for int64 LE, every odd 32-bit word is 0 (values < 512).
__global__ void k_edges(const int* __restrict__ ei, float* __restrict__ At) {
    __shared__ int flag;
    if (threadIdx.x == 0) flag = 0;
    __syncthreads();
    int any = 0;
    for (int i = threadIdx.x; i < EE; i += blockDim.x) any |= ei[2 * i + 1];
    if (any) atomicOr(&flag, 1);
    __syncthreads();
    const bool is32 = (flag != 0);
    for (int e = threadIdx.x; e < EE; e += blockDim.x) {
        int src, dst;
        if (is32) { src = ei[e];     dst = ei[EE + e]; }
        else      { src = ei[2 * e]; dst = ei[2 * (EE + e)]; }
        atomicAdd(&At[dst * NN + src], 1.0f);
    }
}

__global__ void k_cast_at(const float* __restrict__ At, short* __restrict__ Atb) {
    int t = blockIdx.x * 256 + threadIdx.x;
    Atb[t] = f2bf(At[t]);
}

// Wt2[s][n][d] = bf16(W[(s*128+d)*128 + n])
__global__ void k_wt2(const float* __restrict__ W, short* __restrict__ Wt2) {
    int t = blockIdx.x * 256 + threadIdx.x;     // t = kk*128 + n, kk = s*128+d
    int kk = t >> 7, n = t & 127;
    int s = kk >> 7, d = kk & 127;
    Wt2[s * 16384 + n * 128 + d] = f2bf(W[t]);
}

// ---------------- k_y: Y1T / Y2 from one pass over X ----------------
// block b: i = b>>2, j0 = (b&3)*128; rows m = (i, j0+r).
// Y1T[i][n][j] = bf16( sum_d X[i][j][d] W1[d][n] )   (transposed in epilogue)
// Y2 [i][j][n] = bf16( sum_d X[i][j][d] W2[d][n] )   (natural)
__global__ __launch_bounds__(256) void k_y(const float* __restrict__ X,
                                           const short* __restrict__ Wt2,
                                           short* __restrict__ Y1T,
                                           short* __restrict__ Y2) {
    __shared__ __align__(16) short Xs[16384];   // [kb][r][64 swizzled]
    __shared__ __align__(16) short Ws[16384];   // [kb][n][64 swizzled]; epilogue scratch

    const int tid  = threadIdx.x;
    const int lane = tid & 63;
    const int wv   = tid >> 6;
    const int wr   = (wv >> 1) * 64;
    const int wc   = (wv & 1) * 64;
    const int lm   = lane & 15;
    const int lq   = lane >> 4;
    const int i  = blockIdx.x >> 2;
    const int j0 = (blockIdx.x & 3) * 128;

    // stage X tile once: fp32 -> bf16, contiguous 64 KB region, coalesced
    #pragma unroll
    for (int it = 0; it < 16; ++it) {
        int g = tid + it * 256;
        int r = g >> 5, c4 = g & 31;
        float4 v = *(const float4*)&X[i * 65536 + (j0 + r) * 128 + c4 * 4];
        int kb = c4 >> 4, c = c4 & 15, p = c >> 1, h2 = c & 1;
        bf16x4 pc; pc[0] = f2bf(v.x); pc[1] = f2bf(v.y); pc[2] = f2bf(v.z); pc[3] = f2bf(v.w);
        *(bf16x4*)&Xs[kb * 8192 + r * 64 + ((p ^ (r & 7)) * 8 + h2 * 4)] = pc;
    }

    #pragma unroll
    for (int s = 1; s <= 2; ++s) {
        // stage W[s] (both kb halves): dest linear, src chunk XOR-swizzled
        #pragma unroll
        for (int it = 0; it < 8; ++it) {
            int slot = it * 256 + tid;              // = kb*1024 + n*8 + pc
            int kb = slot >> 10, rem = slot & 1023;
            int n = rem >> 3, pc = rem & 7;
            gll16(&Ws[slot * 8],
                  &Wt2[s * 16384 + n * 128 + kb * 64 + ((pc ^ (n & 7)) * 8)]);
        }
        __syncthreads();

        f32x4 acc[4][4] = {};
        #pragma unroll
        for (int kb = 0; kb < 2; ++kb)
            #pragma unroll
            for (int ks = 0; ks < 2; ++ks) {
                bf16x8 af[4], bf[4];
                #pragma unroll
                for (int mf = 0; mf < 4; ++mf) {
                    int R = wr + mf * 16 + lm, Cc = ks * 4 + lq;
                    af[mf] = *(const bf16x8*)&Xs[kb * 8192 + R * 64 + (Cc ^ (R & 7)) * 8];
                }
                #pragma unroll
                for (int nf = 0; nf < 4; ++nf) {
                    int R = wc + nf * 16 + lm, Cc = ks * 4 + lq;
                    bf[nf] = *(const bf16x8*)&Ws[kb * 8192 + R * 64 + (Cc ^ (R & 7)) * 8];
                }
                #pragma unroll
                for (int mf = 0; mf < 4; ++mf)
                    #pragma unroll
                    for (int nf = 0; nf < 4; ++nf)
                        acc[mf][nf] = __builtin_amdgcn_mfma_f32_16x16x32_bf16(
                            af[mf], bf[nf], acc[mf][nf], 0, 0, 0);
            }
        __syncthreads();   // MFMA reads of Ws done -> safe to reuse as scratch

        if (s == 1) {
            // transposed epilogue: T[n][j] u32-pairs, XOR-swizzled, b64 writes
            u32* T = (u32*)Ws;
            #pragma unroll
            for (int mf = 0; mf < 4; ++mf)
                #pragma unroll
                for (int nf = 0; nf < 4; ++nf) {
                    int n = wc + nf * 16 + lm;
                    int jb = wr + mf * 16 + lq * 4;   // multiple of 4
                    int w = jb >> 1;                   // even
                    u32 lo = pk2(acc[mf][nf][0], acc[mf][nf][1]);
                    u32 hi = pk2(acc[mf][nf][2], acc[mf][nf][3]);
                    uint2 val; val.x = lo; val.y = hi;
                    *(uint2*)&T[n * 64 + (w ^ (n & 28))] = val;
                }
            __syncthreads();
            #pragma unroll
            for (int it = 0; it < 8; ++it) {
                int ch = tid & 15, n = (tid >> 4) + it * 16;
                uint4 q = *(const uint4*)&T[n * 64 + ((ch * 4) ^ (n & 28))];
                *(uint4*)&Y1T[i * 65536 + n * 512 + j0 + ch * 8] = q;
            }
            __syncthreads();   // before s=2 W staging overwrites T
        } else {
            // natural epilogue via LDS round-trip -> coalesced 16B stores
            #pragma unroll
            for (int mf = 0; mf < 4; ++mf)
                #pragma unroll
                for (int nf = 0; nf < 4; ++nf)
                    #pragma unroll
                    for (int r = 0; r < 4; ++r)
                        Ws[(wr + mf * 16 + lq * 4 + r) * 128 + wc + nf * 16 + lm]
                            = f2bf(acc[mf][nf][r]);
            __syncthreads();
            #pragma unroll
            for (int it = 0; it < 8; ++it) {
                int q = tid + it * 256;
                int row = q >> 4, oc = (q & 15) * 8;
                *(bf16x8*)&Y2[i * 65536 + (j0 + row) * 128 + oc]
                    = *(const bf16x8*)&Ws[row * 128 + oc];
            }
        }
    }
}

// ---------------- k_t: bf16 transpose Y2[k][j][n] -> Y2T[j][n][k] ----------------
// block b: j = b>>2, k0 = (b&3)*128. Pair-packed u32 LDS tile, vector both sides.
__global__ __launch_bounds__(256) void k_t(const short* __restrict__ Y2,
                                           short* __restrict__ Y2T) {
    __shared__ __align__(16) u32 U[128 * 64];   // U[n][a]: (k=2a, 2a+1) packed
    const int tid = threadIdx.x;
    const int j  = blockIdx.x >> 2;
    const int k0 = (blockIdx.x & 3) * 128;

    const int c8 = tid & 15;         // 8-n chunk
    const int a0 = tid >> 4;         // pair index base
    #pragma unroll
    for (int it = 0; it < 4; ++it) {
        int a = a0 + it * 16;        // 0..63
        const short* r0 = &Y2[(size_t)(k0 + 2 * a) * 65536 + j * 128 + c8 * 8];
        bf16x8 A0 = *(const bf16x8*)r0;
        bf16x8 A1 = *(const bf16x8*)(r0 + 65536);
        #pragma unroll
        for (int cc = 0; cc < 8; ++cc) {
            int n = c8 * 8 + cc;
            U[n * 64 + (a ^ (n & 28))] =
                (u32)(unsigned short)A0[cc] | ((u32)(unsigned short)A1[cc] << 16);
        }
    }
    __syncthreads();
    const int ch = tid & 15;
    const int n0 = tid >> 4;
    #pragma unroll
    for (int it = 0; it < 8; ++it) {
        int n = n0 + it * 16;
        uint4 q = *(const uint4*)&U[n * 64 + ((ch * 4) ^ (n & 28))];
        *(uint4*)&Y2T[j * 65536 + n * 512 + k0 + ch * 8] = q;
    }
}

// ---------------- k_a1: P1[i][j][n] = sum_k At[j,k] Y1T[i][n][k] ----------------
// m97 structure; block b: i = b>>2, jt = b&3.
__global__ __launch_bounds__(256) void k_a1(const short* __restrict__ Atb,
                                            const short* __restrict__ Y1T,
                                            short* __restrict__ P1) {
    __shared__ __align__(16) short sm[16384];
    short* As = sm;
    short* Bs = sm + 8192;

    const int tid  = threadIdx.x;
    const int lane = tid & 63;
    const int wv   = tid >> 6;
    const int wr   = (wv >> 1) * 64;
    const int wc   = (wv & 1) * 64;
    const int lm   = lane & 15;
    const int lq   = lane >> 4;
    const int i  = blockIdx.x >> 2;
    const int a0 = (blockIdx.x & 3) * 128;

    f32x4 acc[4][4] = {};

    for (int kb = 0; kb < 8; ++kb) {
        const int k0 = kb * 64;
        #pragma unroll
        for (int it = 0; it < 4; ++it) {
            int slot = it * 256 + tid;
            int r = slot >> 3, p = slot & 7;
            int cg = (p ^ (r & 7)) * 8;
            gll16(&As[slot * 8], &Atb[(a0 + r) * 512 + k0 + cg]);
            gll16(&Bs[slot * 8], &Y1T[i * 65536 + r * 512 + k0 + cg]);
        }
        __syncthreads();
        #pragma unroll
        for (int ks = 0; ks < 2; ++ks) {
            bf16x8 af[4], bf[4];
            #pragma unroll
            for (int mf = 0; mf < 4; ++mf) {
                int R = wr + mf * 16 + lm, Cc = ks * 4 + lq;
                af[mf] = *(const bf16x8*)&As[R * 64 + (Cc ^ (R & 7)) * 8];
            }
            #pragma unroll
            for (int nf = 0; nf < 4; ++nf) {
                int R = wc + nf * 16 + lm, Cc = ks * 4 + lq;
                bf[nf] = *(const bf16x8*)&Bs[R * 64 + (Cc ^ (R & 7)) * 8];
            }
            #pragma unroll
            for (int mf = 0; mf < 4; ++mf)
                #pragma unroll
                for (int nf = 0; nf < 4; ++nf)
                    acc[mf][nf] = __builtin_amdgcn_mfma_f32_16x16x32_bf16(
                        af[mf], bf[nf], acc[mf][nf], 0, 0, 0);
        }
        __syncthreads();
    }

    #pragma unroll
    for (int mf = 0; mf < 4; ++mf)
        #pragma unroll
        for (int nf = 0; nf < 4; ++nf)
            #pragma unroll
            for (int r = 0; r < 4; ++r)
                sm[(wr + mf * 16 + lq * 4 + r) * 128 + wc + nf * 16 + lm]
                    = f2bf(acc[mf][nf][r]);
    __syncthreads();
    #pragma unroll
    for (int it = 0; it < 8; ++it) {
        int q = tid + it * 256;
        int row = q >> 4, oc = (q & 15) * 8;
        *(bf16x8*)&P1[i * 65536 + (a0 + row) * 128 + oc]
            = *(const bf16x8*)&sm[row * 128 + oc];
    }
}

// ---------------- k_a2f: out = At@Y2T + X@W0 + P1 + b ----------------
// block b: j = b>>2, i0 = (b&3)*128; out rows (i0+r, j), cols n.
__global__ __launch_bounds__(256) void k_a2f(const float* __restrict__ X,
                                             const short* __restrict__ Atb,
                                             const short* __restrict__ Y2T,
                                             const short* __restrict__ Wt2,
                                             const short* __restrict__ P1,
                                             const float* __restrict__ bias,
                                             float* __restrict__ out) {
    __shared__ __align__(16) short sm[16384];
    short* As = sm;
    short* Bs = sm + 8192;

    const int tid  = threadIdx.x;
    const int lane = tid & 63;
    const int wv   = tid >> 6;
    const int wr   = (wv >> 1) * 64;
    const int wc   = (wv & 1) * 64;
    const int lm   = lane & 15;
    const int lq   = lane >> 4;
    const int j  = blockIdx.x >> 2;
    const int i0 = (blockIdx.x & 3) * 128;

    f32x4 acc[4][4] = {};

    // ---- phase 1: X@W0, K=128 (contract over d, no transpose needed) ----
    #pragma unroll
    for (int kb = 0; kb < 2; ++kb) {
        // A: X[(i0+r), j, kb*64 + d'] fp32 -> bf16, register path
        #pragma unroll
        for (int it = 0; it < 8; ++it) {
            int g = tid + it * 256;
            int r = g >> 4, c4 = g & 15;
            float4 v = *(const float4*)&X[(size_t)(i0 + r) * 65536 + j * 128 + kb * 64 + c4 * 4];
            int p = c4 >> 1, h2 = c4 & 1;
            bf16x4 pc; pc[0] = f2bf(v.x); pc[1] = f2bf(v.y); pc[2] = f2bf(v.z); pc[3] = f2bf(v.w);
            *(bf16x4*)&As[r * 64 + ((p ^ (r & 7)) * 8 + h2 * 4)] = pc;
        }
        // B: W0 chunk via gll16
        #pragma unroll
        for (int it = 0; it < 4; ++it) {
            int slot = it * 256 + tid;
            int n = slot >> 3, pc = slot & 7;
            gll16(&Bs[slot * 8], &Wt2[n * 128 + kb * 64 + ((pc ^ (n & 7)) * 8)]);
        }
        __syncthreads();
        #pragma unroll
        for (int ks = 0; ks < 2; ++ks) {
            bf16x8 af[4], bf[4];
            #pragma unroll
            for (int mf = 0; mf < 4; ++mf) {
                int R = wr + mf * 16 + lm, Cc = ks * 4 + lq;
                af[mf] = *(const bf16x8*)&As[R * 64 + (Cc ^ (R & 7)) * 8];
            }
            #pragma unroll
            for (int nf = 0; nf < 4; ++nf) {
                int R = wc + nf * 16 + lm, Cc = ks * 4 + lq;
                bf[nf] = *(const bf16x8*)&Bs[R * 64 + (Cc ^ (R & 7)) * 8];
            }
            #pragma unroll
            for (int mf = 0; mf < 4; ++mf)
                #pragma unroll
                for (int nf = 0; nf < 4; ++nf)
                    acc[mf][nf] = __builtin_amdgcn_mfma_f32_16x16x32_bf16(
                        af[mf], bf[nf], acc[mf][nf], 0, 0, 0);
        }
        __syncthreads();
    }

    // ---- phase 2: At@Y2T, K=512 ----
    for (int kb = 0; kb < 8; ++kb) {
        const int k0 = kb * 64;
        #pragma unroll
        for (int it = 0; it < 4; ++it) {
            int slot = it * 256 + tid;
            int r = slot >> 3, p = slot & 7;
            int cg = (p ^ (r & 7)) * 8;
            gll16(&As[slot * 8], &Atb[(i0 + r) * 512 + k0 + cg]);
            gll16(&Bs[slot * 8], &Y2T[j * 65536 + r * 512 + k0 + cg]);
        }
        __syncthreads();
        #pragma unroll
        for (int ks = 0; ks < 2; ++ks) {
            bf16x8 af[4], bf[4];
            #pragma unroll
            for (int mf = 0; mf < 4; ++mf) {
                int R = wr + mf * 16 + lm, Cc = ks * 4 + lq;
                af[mf] = *(const bf16x8*)&As[R * 64 + (Cc ^ (R & 7)) * 8];
            }
            #pragma unroll
            for (int nf = 0; nf < 4; ++nf) {
                int R = wc + nf * 16 + lm, Cc = ks * 4 + lq;
                bf[nf] = *(const bf16x8*)&Bs[R * 64 + (Cc ^ (R & 7)) * 8];
            }
            #pragma unroll
            for (int mf = 0; mf < 4; ++mf)
                #pragma unroll
                for (int nf = 0; nf < 4; ++nf)
                    acc[mf][nf] = __builtin_amdgcn_mfma_f32_16x16x32_bf16(
                        af[mf], bf[nf], acc[mf][nf], 0, 0, 0);
        }
        __syncthreads();
    }

    // ---- fused epilogue: + P1 + bias -> fp32 out ----
    #pragma unroll
    for (int mf = 0; mf < 4; ++mf)
        #pragma unroll
        for (int nf = 0; nf < 4; ++nf)
            #pragma unroll
            for (int r = 0; r < 4; ++r)
                sm[(wr + mf * 16 + lq * 4 + r) * 128 + wc + nf * 16 + lm]
                    = f2bf(acc[mf][nf][r]);
    __syncthreads();
    #pragma unroll
    for (int it = 0; it < 8; ++it) {
        int q = tid + it * 256;
        int row = q >> 4, oc = (q & 15) * 8;
        bf16x8 vs = *(const bf16x8*)&sm[row * 128 + oc];
        bf16x8 vp = *(const bf16x8*)&P1[(size_t)(i0 + row) * 65536 / 512 * 512 + 0];
        // (recomputed below properly; see vpl)
        (void)vp;
        const short* p1p = &P1[(size_t)(i0 + row) * 65536 + j * 128 + oc];
        bf16x8 vpl = *(const bf16x8*)p1p;
        float4 b0 = *(const float4*)&bias[oc];
        float4 b1 = *(const float4*)&bias[oc + 4];
        union { short s; __hip_bfloat16 h; } cs, cp;
        float o[8];
        #pragma unroll
        for (int e = 0; e < 8; ++e) {
            cs.s = vs[e]; cp.s = vpl[e];
            o[e] = __bfloat162float(cs.h) + __bfloat162float(cp.h);
        }
        o[0] += b0.x; o[1] += b0.y; o[2] += b0.z; o[3] += b0.w;
        o[4] += b1.x; o[5] += b1.y; o[6] += b1.z; o[7] += b1.w;
        float* op = &out[(size_t)(i0 + row) * 65536 + j * 128 + oc];
        float4 w0; w0.x = o[0]; w0.y = o[1]; w0.z = o[2]; w0.w = o[3];
        float4 w1; w1.x = o[4]; w1.y = o[5]; w1.z = o[6]; w1.w = o[7];
        *(float4*)op = w0;
        *(float4*)(op + 4) = w1;
    }
}

// ================= fallback path (round-1, proven, 130 MiB ws) =================

__global__ __launch_bounds__(256) void k_agg_fb(const float* __restrict__ X,
                                                const float* __restrict__ At,
                                                short* __restrict__ X1b,
                                                short* __restrict__ X2b) {
    __shared__ short As[128 * 72];
    __shared__ short Bs[128 * 72];
    const int tid  = threadIdx.x;
    const int lane = tid & 63;
    const int wv   = tid >> 6;
    const int wr   = (wv >> 1) * 64;
    const int wc   = (wv & 1) * 64;
    const int lm   = lane & 15;
    const int lq   = lane >> 4;
    int a0, Bbase, Bks, Cbase, Crs;
    short* Cp;
    const int bidx = blockIdx.x;
    if (bidx < 2048) {
        int i = bidx >> 2, jt = bidx & 3;
        a0 = jt * 128; Bbase = i * 65536; Bks = 128;
        Cbase = i * 65536 + jt * 16384; Crs = 128; Cp = X1b;
    } else {
        int bb = bidx - 2048;
        int j = bb >> 2, it = bb & 3;
        a0 = it * 128; Bbase = j * 128; Bks = 65536;
        Cbase = it * 8388608 + j * 128; Crs = 65536; Cp = X2b;
    }
    f32x4 acc[4][4] = {};
    const int d  = tid & 127;
    const int kh = tid >> 7;
    for (int kb = 0; kb < 8; ++kb) {
        const int k0 = kb * 64;
        #pragma unroll
        for (int it8 = 0; it8 < 8; ++it8) {
            int g = tid + it8 * 256;
            int r = g >> 4, kq = (g & 15) * 4;
            float4 v = *(const float4*)&At[(a0 + r) * 512 + k0 + kq];
            bf16x4 p; p[0] = f2bf(v.x); p[1] = f2bf(v.y); p[2] = f2bf(v.z); p[3] = f2bf(v.w);
            *(bf16x4*)&As[r * 72 + kq] = p;
        }
        #pragma unroll
        for (int gi = 0; gi < 4; ++gi) {
            int kg = kh * 4 + gi;
            bf16x8 p;
            #pragma unroll
            for (int jj = 0; jj < 8; ++jj)
                p[jj] = f2bf(X[Bbase + (k0 + kg * 8 + jj) * Bks + d]);
            *(bf16x8*)&Bs[d * 72 + kg * 8] = p;
        }
        __syncthreads();
        #pragma unroll
        for (int ks = 0; ks < 2; ++ks) {
            bf16x8 af[4], bfr[4];
            #pragma unroll
            for (int mf = 0; mf < 4; ++mf)
                af[mf] = *(const bf16x8*)&As[(wr + mf * 16 + lm) * 72 + ks * 32 + lq * 8];
            #pragma unroll
            for (int nf = 0; nf < 4; ++nf)
                bfr[nf] = *(const bf16x8*)&Bs[(wc + nf * 16 + lm) * 72 + ks * 32 + lq * 8];
            #pragma unroll
            for (int mf = 0; mf < 4; ++mf)
                #pragma unroll
                for (int nf = 0; nf < 4; ++nf)
                    acc[mf][nf] = __builtin_amdgcn_mfma_f32_16x16x32_bf16(
                        af[mf], bfr[nf], acc[mf][nf], 0, 0, 0);
        }
        __syncthreads();
    }
    #pragma unroll
    for (int mf = 0; mf < 4; ++mf)
        #pragma unroll
        for (int nf = 0; nf < 4; ++nf)
            #pragma unroll
            for (int r = 0; r < 4; ++r) {
                int row = wr + mf * 16 + lq * 4 + r;
                int col = wc + nf * 16 + lm;
                Cp[Cbase + row * Crs + col] = f2bf(acc[mf][nf][r]);
            }
}

__global__ __launch_bounds__(256) void k_final_fb(const float* __restrict__ X,
                                                  const short* __restrict__ X1b,
                                                  const short* __restrict__ X2b,
                                                  const short* __restrict__ Wt2,
                                                  const float* __restrict__ bias,
                                                  float* __restrict__ out) {
    __shared__ short As[128 * 72];
    __shared__ short Ws[128 * 72];
    const int tid  = threadIdx.x;
    const int lane = tid & 63;
    const int wv   = tid >> 6;
    const int wr   = (wv >> 1) * 64;
    const int wc   = (wv & 1) * 64;
    const int lm   = lane & 15;
    const int lq   = lane >> 4;
    const int m0   = blockIdx.x * 128;
    f32x4 acc[4][4] = {};
    for (int ph = 0; ph < 6; ++ph) {
        const int s = ph >> 1, h = ph & 1;
        if (s == 0) {
            #pragma unroll
            for (int it8 = 0; it8 < 8; ++it8) {
                int g = tid + it8 * 256;
                int r = g >> 4, kq = (g & 15) * 4;
                float4 v = *(const float4*)&X[(m0 + r) * 128 + h * 64 + kq];
                bf16x4 p; p[0] = f2bf(v.x); p[1] = f2bf(v.y); p[2] = f2bf(v.z); p[3] = f2bf(v.w);
                *(bf16x4*)&As[r * 72 + kq] = p;
            }
        } else {
            const short* src = (s == 1) ? X1b : X2b;
            #pragma unroll
            for (int it4 = 0; it4 < 4; ++it4) {
                int g = tid + it4 * 256;
                int r = g >> 3, ko = (g & 7) * 8;
                *(bf16x8*)&As[r * 72 + ko] =
                    *(const bf16x8*)&src[(m0 + r) * 128 + h * 64 + ko];
            }
        }
        #pragma unroll
        for (int it4 = 0; it4 < 4; ++it4) {
            int g = tid + it4 * 256;
            int n = g >> 3, ko = (g & 7) * 8;
            *(bf16x8*)&Ws[n * 72 + ko] =
                *(const bf16x8*)&Wt2[s * 16384 + n * 128 + h * 64 + ko];
        }
        __syncthreads();
        #pragma unroll
        for (int ks = 0; ks < 2; ++ks) {
            bf16x8 af[4], bfr[4];
            #pragma unroll
            for (int mf = 0; mf < 4; ++mf)
                af[mf] = *(const bf16x8*)&As[(wr + mf * 16 + lm) * 72 + ks * 32 + lq * 8];
            #pragma unroll
            for (int nf = 0; nf < 4; ++nf)
                bfr[nf] = *(const bf16x8*)&Ws[(wc + nf * 16 + lm) * 72 + ks * 32 + lq * 8];
            #pragma unroll
            for (int mf = 0; mf < 4; ++mf)
                #pragma unroll
                for (int nf = 0; nf < 4; ++nf)
                    acc[mf][nf] = __builtin_amdgcn_mfma_f32_16x16x32_bf16(
                        af[mf], bfr[nf], acc[mf][nf], 0, 0, 0);
        }
        __syncthreads();
    }
    #pragma unroll
    for (int nf = 0; nf < 4; ++nf) {
        float bv = bias[wc + nf * 16 + lm];
        #pragma unroll
        for (int mf = 0; mf < 4; ++mf)
            #pragma unroll
            for (int r = 0; r < 4; ++r) {
                int row = m0 + wr + mf * 16 + lq * 4 + r;
                int col = wc + nf * 16 + lm;
                out[row * 128 + col] = acc[mf][nf][r] + bv;
            }
    }
}

extern "C" void kernel_launch(void* const* d_in, const int* in_sizes, int n_in,
                              void* d_out, int out_size, void* d_ws, size_t ws_size,
                              hipStream_t stream) {
    const float* X  = (const float*)d_in[0];
    const int*   ei = (const int*)d_in[1];
    const float* W  = (const float*)d_in[2];
    const float* b  = (const float*)d_in[3];
    float* out = (float*)d_out;
    char* ws = (char*)d_ws;
    const size_t MB = 1u << 20;

    float* At  = (float*)ws;                            // 1 MiB
    short* Atb = (short*)(ws + 1 * MB);                 // 0.5 MiB
    short* Wt2 = (short*)(ws + 1 * MB + 512 * 1024);    // 96 KiB

    k_zero   <<<1024, 256, 0, stream>>>(At);
    k_edges  <<<1, 1024, 0, stream>>>(ei, At);
    k_wt2    <<<192, 256, 0, stream>>>(W, Wt2);
    k_cast_at<<<1024, 256, 0, stream>>>(At, Atb);

    if (ws_size >= 194 * MB) {
        // Y1T @2M (64M), Y2 @66M (64M, reused as P1 after k_t), Y2T @130M (64M)
        short* Y1T = (short*)(ws + 2 * MB);
        short* Y2  = (short*)(ws + 66 * MB);
        short* Y2T = (short*)(ws + 130 * MB);
        short* P1  = Y2;   // alias: Y2 dead after k_t
        k_y  <<<2048, 256, 0, stream>>>(X, Wt2, Y1T, Y2);
        k_t  <<<2048, 256, 0, stream>>>(Y2, Y2T);
        k_a1 <<<2048, 256, 0, stream>>>(Atb, Y1T, P1);
        k_a2f<<<2048, 256, 0, stream>>>(X, Atb, Y2T, Wt2, P1, b, out);
    } else {
        short* X1b = (short*)(ws + 2 * MB);
        short* X2b = (short*)(ws + 66 * MB);
        k_agg_fb  <<<4096, 256, 0, stream>>>(X, At, X1b, X2b);
        k_final_fb<<<2048, 256, 0, stream>>>(X, X1b, X2b, Wt2, b, out);
    }
}